// Round 9
// baseline (167.547 us; speedup 1.0000x reference)
//
#include <hip/hip_runtime.h>
#include <math.h>

#define B_ 16
#define N_ 8400
#define M_ 32
#define C_ 80
#define TOPK_ 13
#define KL_ 16            // sentinel-padded list length for bitonic merges
#define MAXC_ 2048        // per-row candidate capacity (max possible ~1460)
#define MZ_ 4             // m-split factor for k_cand
#define MG_ (M_ / MZ_)    // 8 gts per k_cand block

// ---------------------------------------------------------------------------
__device__ __forceinline__ bool in_gt(double ax, double ay,
    double gx1, double gy1, double gx2, double gy2) {
  return (ax - gx1 > 1e-9) && (ay - gy1 > 1e-9) &&
         (gx2 - ax > 1e-9) && (gy2 - ay > 1e-9);
}

// CIoU clipped at 0 — identical formula/order as all passing rounds.
__device__ __forceinline__ double ciou_ov(
    double px1, double py1, double px2, double py2,
    double gx1, double gy1, double gx2, double gy2,
    double atp, double atg) {
  double iw = fmin(gx2, px2) - fmax(gx1, px1); iw = iw > 0.0 ? iw : 0.0;
  double ih = fmin(gy2, py2) - fmax(gy1, py1); ih = ih > 0.0 ? ih : 0.0;
  double inter = iw * ih;
  double w1 = gx2 - gx1, h1 = gy2 - gy1 + 1e-7;
  double w2 = px2 - px1, h2 = py2 - py1 + 1e-7;
  double uni = w1 * h1 + w2 * h2 - inter + 1e-7;
  double iou = inter / uni;
  double cw = fmax(gx2, px2) - fmin(gx1, px1);
  double ch = fmax(gy2, py2) - fmin(gy1, py1);
  double c2 = cw * cw + ch * ch + 1e-7;
  double dx = px1 + px2 - gx1 - gx2, dy = py1 + py2 - gy1 - gy2;
  double rho2 = (dx * dx + dy * dy) * 0.25;
  double dv = atp - atg;
  double v = (4.0 / (M_PI * M_PI)) * dv * dv;
  double a = v / (v - iou + (1.0 + 1e-7));
  double c = iou - (rho2 / c2 + v * a);
  return c > 0.0 ? c : 0.0;
}

#define MERGE_LISTS(av, ai, bv, bi)                                          \
  {                                                                          \
    _Pragma("unroll")                                                        \
    for (int j = 0; j < KL_; ++j) {                                          \
      double vb = bv[KL_ - 1 - j]; int ib = bi[KL_ - 1 - j];                 \
      bool take = (vb > av[j]) || (vb == av[j] && ib < ai[j]);               \
      av[j] = take ? vb : av[j];                                             \
      ai[j] = take ? ib : ai[j];                                             \
    }                                                                        \
    _Pragma("unroll")                                                        \
    for (int dd = 8; dd >= 1; dd >>= 1) {                                    \
      _Pragma("unroll")                                                      \
      for (int j = 0; j < KL_; ++j) {                                        \
        if (!(j & dd)) {                                                     \
          int kk = j | dd;                                                   \
          bool sw = (av[kk] > av[j]) ||                                      \
                    (av[kk] == av[j] && ai[kk] < ai[j]);                     \
          double xv = av[j]; int xi = ai[j];                                 \
          av[j] = sw ? av[kk] : av[j]; ai[j] = sw ? ai[kk] : ai[j];          \
          av[kk] = sw ? xv : av[kk];   ai[kk] = sw ? xi : ai[kk];            \
        }                                                                    \
      }                                                                      \
    }                                                                        \
  }

// ---------------------------------------------------------------------------
// P0 (2 blocks): robust mask decode + zero CNT/PAL/POV.
__global__ __launch_bounds__(256) void k_prep0(
    const unsigned char* __restrict__ raw, unsigned char* __restrict__ mask,
    unsigned int* __restrict__ CNT,
    unsigned int* __restrict__ PAL, unsigned int* __restrict__ POV) {
  int gid = blockIdx.x * 256 + threadIdx.x;
  if (gid < B_ * M_) { CNT[gid] = 0u; PAL[gid] = 0u; POV[gid] = 0u; }
  if (blockIdx.x == 0) {
    __shared__ int s_bad;
    int t = threadIdx.x;
    if (t == 0) s_bad = 0;
    __syncthreads();
    if (t < B_) {
      int cnt = 0; bool seen0 = false; bool bad = false;
      for (int m = 0; m < M_; ++m) {
        unsigned char v = raw[t * M_ + m];
        if (v > 1) { bad = true; break; }
        if (v) { if (seen0) { bad = true; break; } ++cnt; }
        else seen0 = true;
      }
      if (cnt < 1) bad = true;
      if (bad) atomicOr(&s_bad, 1);
    }
    __syncthreads();
    bool ok = (s_bad == 0);
    const int* ri = (const int*)raw;
    for (int i = t; i < B_ * M_; i += 256)
      mask[i] = ok ? (raw[i] ? 1 : 0) : ((ri[i] != 0) ? 1 : 0);
  }
}

// ---------------------------------------------------------------------------
// K1: anchor-parallel candidate generation. grid (33, B, MZ_) = 2112 blocks.
// z==0 slice also zero-fills MPB (cand never reads it; rowsel runs after).
// atan_g computed inline at staging (8 per block, bit-identical formula).
__global__ __launch_bounds__(256) void k_cand(
    const float* __restrict__ pd_scores, const float* __restrict__ pd_bboxes,
    const float* __restrict__ anc, const int* __restrict__ gt_labels,
    const float* __restrict__ gt_bboxes, const unsigned char* __restrict__ mask,
    unsigned int* __restrict__ MPB,
    unsigned int* __restrict__ CNT, double* __restrict__ CV,
    int* __restrict__ CI) {
  int b = blockIdx.y, t = threadIdx.x;
  int m0 = blockIdx.z * MG_;
  int n = blockIdx.x * 256 + t;

  if (blockIdx.z == 0 && n < N_) MPB[(size_t)b * N_ + n] = 0u;

  __shared__ double s_g[MG_][4];
  __shared__ double s_atg[MG_];
  __shared__ int s_cls[MG_];
  __shared__ unsigned char s_msk[MG_];
  __shared__ int s_any;
  if (t == 0) s_any = 0;
  __syncthreads();
  if (t < MG_) {
    int row = b * M_ + m0 + t;
    unsigned char mk = mask[row];
    s_msk[t] = mk;
    if (mk) atomicOr(&s_any, 1);
    double x1 = (double)gt_bboxes[row * 4 + 0], y1 = (double)gt_bboxes[row * 4 + 1];
    double x2 = (double)gt_bboxes[row * 4 + 2], y2 = (double)gt_bboxes[row * 4 + 3];
    s_g[t][0] = x1; s_g[t][1] = y1; s_g[t][2] = x2; s_g[t][3] = y2;
    s_atg[t] = atan((x2 - x1) / (y2 - y1 + 1e-7));
    s_cls[t] = gt_labels[row];
  }
  __syncthreads();
  if (!s_any) return;
  if (n >= N_) return;

  float2 a2 = ((const float2*)anc)[n];
  double ax = (double)a2.x, ay = (double)a2.y;
  bool have = false;
  double px1 = 0, py1 = 0, px2 = 0, py2 = 0, atpn = 0;
  const float* srow = pd_scores + ((size_t)b * N_ + n) * C_;

  for (int mm = 0; mm < MG_; ++mm) {
    if (!s_msk[mm]) continue;
    double gx1 = s_g[mm][0], gy1 = s_g[mm][1], gx2 = s_g[mm][2], gy2 = s_g[mm][3];
    if (!in_gt(ax, ay, gx1, gy1, gx2, gy2)) continue;
    if (!have) {
      float4 pb = ((const float4*)(pd_bboxes + (size_t)b * N_ * 4))[n];
      px1 = (double)pb.x; py1 = (double)pb.y;
      px2 = (double)pb.z; py2 = (double)pb.w;
      atpn = atan((px2 - px1) / ((py2 - py1) + 1e-7));
      have = true;
    }
    double ov = ciou_ov(px1, py1, px2, py2, gx1, gy1, gx2, gy2, atpn, s_atg[mm]);
    double o2 = ov * ov;
    double am = (double)srow[s_cls[mm]] * (o2 * o2 * o2);
    int row = b * M_ + m0 + mm;
    unsigned int idx = atomicAdd(&CNT[row], 1u);
    if (idx < MAXC_) {
      CV[(size_t)row * MAXC_ + idx] = am;
      CI[(size_t)row * MAXC_ + idx] = n;
    }
  }
}

// ---------------------------------------------------------------------------
// K2: one WAVE per row (4 rows/block, no LDS, no barriers). Register top-13
// + wave butterfly; lane 0 builds selection with exact zero-fill; winners
// broadcast by shfl; lane j<13 scatters its MPB bit.
__global__ __launch_bounds__(256) void k_rowsel(
    const double* __restrict__ CV, const int* __restrict__ CI,
    const unsigned int* __restrict__ CNT,
    const float* __restrict__ anc, const float* __restrict__ gt_bboxes,
    const unsigned char* __restrict__ mask, unsigned int* __restrict__ MPB) {
  int t = threadIdx.x;
  int lane = t & 63;
  int row = blockIdx.x * 4 + (t >> 6);
  if (row >= B_ * M_ || !mask[row]) return;
  int b = row >> 5, m = row & 31;
  int cnt = (int)CNT[row]; if (cnt > MAXC_) cnt = MAXC_;
  const double* cv = CV + (size_t)row * MAXC_;
  const int*    ci = CI + (size_t)row * MAXC_;

  double tv[KL_]; int ti[KL_];
#pragma unroll
  for (int j = 0; j < KL_; ++j) { tv[j] = -1.0; ti[j] = 0x7fffffff; }

  for (int i = lane; i < cnt; i += 64) {
    double v = cv[i]; int idx = ci[i];
    if (v > tv[TOPK_ - 1] || (v == tv[TOPK_ - 1] && idx < ti[TOPK_ - 1])) {
      double cvv = v; int cii = idx;
#pragma unroll
      for (int j = 0; j < TOPK_; ++j) {
        bool sw = (cvv > tv[j]) || (cvv == tv[j] && cii < ti[j]);
        double xv = tv[j]; int xi = ti[j];
        if (sw) { tv[j] = cvv; ti[j] = cii; cvv = xv; cii = xi; }
      }
    }
  }

  // within-wave butterfly: all lanes converge to wave top-16
#pragma unroll
  for (int d = 1; d <= 32; d <<= 1) {
    double bv[KL_]; int bi[KL_];
#pragma unroll
    for (int j = 0; j < KL_; ++j) {
      bv[j] = __shfl_xor(tv[j], d, 64);
      bi[j] = __shfl_xor(ti[j], d, 64);
    }
    MERGE_LISTS(tv, ti, bv, bi)
  }

  // lane 0: selection with exact zero-fill emulation of full-array top_k
  int sel[TOPK_]; int p = 0;
  if (lane == 0) {
#pragma unroll
    for (int j = 0; j < TOPK_; ++j) sel[j] = -1;
#pragma unroll
    for (int j = 0; j < TOPK_; ++j)
      if (tv[j] > 0.0) sel[p++] = ti[j];
    int nn = 0, slot = p;
    while (slot < TOPK_) {
      bool ispos = false;
#pragma unroll
      for (int q = 0; q < TOPK_; ++q) ispos |= (q < p && sel[q] == nn);
      if (!ispos) { 
        // static-index store of (nn | tag) into slot
#pragma unroll
        for (int q = 0; q < TOPK_; ++q) if (q == slot) sel[q] = nn | 0x40000000;
        ++slot;
      }
      ++nn;
    }
  }
  int pbc = __shfl(p, 0, 64);
  // broadcast element 'lane' of sel to lane 'lane' (static-index selects)
  int mine = -1;
#pragma unroll
  for (int j = 0; j < TOPK_; ++j) {
    int v = __shfl(sel[j], 0, 64);
    if (lane == j) mine = v;
  }
  if (lane < TOPK_) {
    if (lane < pbc) {
      atomicOr(&MPB[(size_t)b * N_ + mine], 1u << m);  // positive: valid by constr.
    } else {
      int n = mine & 0x3fffffff;                       // fill: needs valid check
      double gx1 = gt_bboxes[row * 4 + 0], gy1 = gt_bboxes[row * 4 + 1];
      double gx2 = gt_bboxes[row * 4 + 2], gy2 = gt_bboxes[row * 4 + 3];
      float2 a2 = ((const float2*)anc)[n];
      if (in_gt((double)a2.x, (double)a2.y, gx1, gy1, gx2, gy2))
        atomicOr(&MPB[(size_t)b * N_ + n], 1u << m);
    }
  }
}

// ---------------------------------------------------------------------------
// K3: per (b,n) resolve assignment; ALSO writes labels/bboxes/fg/tg_idx
// outputs (independent of PAL/POV). Wave-cooperative cnt>1 argmax.
__global__ __launch_bounds__(256) void k_colassign(
    const float* __restrict__ pd_scores, const float* __restrict__ pd_bboxes,
    const float* __restrict__ anc, const int* __restrict__ gt_labels,
    const float* __restrict__ gt_bboxes, const unsigned char* __restrict__ mask,
    const unsigned int* __restrict__ MPB,
    unsigned char* __restrict__ TG, unsigned char* __restrict__ FG,
    float* __restrict__ AMC,
    unsigned int* __restrict__ PAL, unsigned int* __restrict__ POV,
    float* __restrict__ out) {
  int b = blockIdx.y;
  int t = threadIdx.x;
  int n = blockIdx.x * 256 + t;
  int lane = t & 63;
  bool act = (n < N_);

  __shared__ double s_g[M_][4];
  __shared__ double s_atg[M_];
  __shared__ int s_cls[M_];
  __shared__ unsigned char s_msk[M_];
  if (t < M_) {
    int gi = b * M_ + t;
    double x1 = (double)gt_bboxes[gi * 4 + 0], y1 = (double)gt_bboxes[gi * 4 + 1];
    double x2 = (double)gt_bboxes[gi * 4 + 2], y2 = (double)gt_bboxes[gi * 4 + 3];
    s_g[t][0] = x1; s_g[t][1] = y1; s_g[t][2] = x2; s_g[t][3] = y2;
    s_atg[t] = atan((x2 - x1) / (y2 - y1 + 1e-7));
    s_cls[t] = gt_labels[gi];
    s_msk[t] = mask[gi];
  }
  __syncthreads();

  size_t i = (size_t)b * N_ + (act ? n : 0);
  unsigned int mpb = act ? MPB[i] : 0u;
  int cnt = __popc(mpb);

  double ax = 0, ay = 0, px1 = 0, py1 = 0, px2 = 0, py2 = 0;
  if (act && cnt >= 1) {
    float2 a2 = ((const float2*)anc)[n];
    float4 pb = ((const float4*)(pd_bboxes + (size_t)b * N_ * 4))[n];
    ax = (double)a2.x; ay = (double)a2.y;
    px1 = (double)pb.x; py1 = (double)pb.y; px2 = (double)pb.z; py2 = (double)pb.w;
  }

  int tg = 0; unsigned char fg = 0; double ov = 0.0;

  if (act && cnt == 1) {
    fg = 1;
    tg = __ffs(mpb) - 1;
    double atpn = atan((px2 - px1) / ((py2 - py1) + 1e-7));
    double g0 = s_g[tg][0], g1 = s_g[tg][1], g2 = s_g[tg][2], g3 = s_g[tg][3];
    bool val = s_msk[tg] && in_gt(ax, ay, g0, g1, g2, g3);
    ov = val ? ciou_ov(px1, py1, px2, py2, g0, g1, g2, g3, atpn, s_atg[tg]) : 0.0;
  }

  // wave-cooperative handling of rare cnt>1 anchors
  unsigned long long flagged = __ballot(act && cnt > 1);
  while (flagged) {
    int src = __ffsll(flagged) - 1;
    flagged &= flagged - 1;
    double qx  = __shfl(ax, src, 64),  qy  = __shfl(ay, src, 64);
    double q1  = __shfl(px1, src, 64), q2  = __shfl(py1, src, 64);
    double q3  = __shfl(px2, src, 64), q4  = __shfl(py2, src, 64);
    double atq = atan((q3 - q1) / ((q4 - q2) + 1e-7));
    int mm = lane & 31;
    double g0 = s_g[mm][0], g1 = s_g[mm][1], g2 = s_g[mm][2], g3 = s_g[mm][3];
    bool val = s_msk[mm] && in_gt(qx, qy, g0, g1, g2, g3);
    double o = val ? ciou_ov(q1, q2, q3, q4, g0, g1, g2, g3, atq, s_atg[mm]) : 0.0;
    int cm = mm;
#pragma unroll
    for (int d = 1; d < 32; d <<= 1) {
      double oo = __shfl_xor(o, d, 64);
      int    om = __shfl_xor(cm, d, 64);
      if (oo > o || (oo == o && om < cm)) { o = oo; cm = om; }
    }
    if (lane == src) { fg = 1; tg = cm; ov = o; }
  }

  if (!act) return;

  TG[i] = (unsigned char)tg;
  FG[i] = fg;
  if (fg) {
    double o2 = ov * ov;
    double am = (double)pd_scores[i * C_ + s_cls[tg]] * (o2 * o2 * o2);
    float ovf = (float)ov, amf = (float)am;
    AMC[i] = amf;
    atomicMax(&PAL[b * M_ + tg], __float_as_uint(amf));
    atomicMax(&POV[b * M_ + tg], __float_as_uint(ovf));
  }

  // aux outputs (independent of PAL/POV)
  float* o0 = out;                         // labels  (B,N)
  float* o1 = out + (size_t)B_ * N_;       // bboxes  (B,N,4)
  float* o3 = out + (size_t)B_ * N_ * 85;  // fg_mask (B,N)
  float* o4 = out + (size_t)B_ * N_ * 86;  // tg_idx  (B,N)
  o0[i] = (float)s_cls[tg];
  o3[i] = fg ? 1.0f : 0.0f;
  o4[i] = (float)tg;
  ((float4*)o1)[i] = make_float4((float)s_g[tg][0], (float)s_g[tg][1],
                                 (float)s_g[tg][2], (float)s_g[tg][3]);
}

// ---------------------------------------------------------------------------
// K4: score stream writer only (43MB), one-hot x norm_align.
__global__ __launch_bounds__(256) void k_sc(
    const int* __restrict__ gt_labels,
    const unsigned char* __restrict__ TG, const unsigned char* __restrict__ FG,
    const float* __restrict__ AMC,
    const unsigned int* __restrict__ PAL, const unsigned int* __restrict__ POV,
    float* __restrict__ out) {
  int b = blockIdx.y;
  int n0 = blockIdx.x * 64;
  int t = threadIdx.x;

  __shared__ int s_cls[M_];
  __shared__ float s_pal[M_], s_pov[M_];
  __shared__ float s_na[64];
  __shared__ int   s_lab[64];
  if (t < M_) {
    int gi = b * M_ + t;
    s_cls[t] = gt_labels[gi];
    s_pal[t] = __uint_as_float(PAL[gi]);
    s_pov[t] = __uint_as_float(POV[gi]);
  }
  __syncthreads();

  if (t < 64) {
    int n = n0 + t;
    if (n < N_) {
      size_t i = (size_t)b * N_ + n;
      int tg = TG[i];
      float na = 0.0f;
      if (FG[i]) {
        double am = (double)AMC[i];
        na = (float)(am * (double)s_pov[tg] / ((double)s_pal[tg] + 1e-9));
      }
      s_na[t] = na; s_lab[t] = s_cls[tg];
    }
  }
  __syncthreads();

  float* o2 = out + (size_t)B_ * N_ * 5;   // scores (B,N,C)
#pragma unroll
  for (int k = 0; k < 5; ++k) {
    int id = t + k * 256;
    int a = id / 20, j = id % 20;
    int n = n0 + a;
    if (n < N_) {
      int lab = s_lab[a];
      float na = s_na[a];
      int c0 = 4 * j;
      float4 w;
      w.x = (c0 + 0 == lab) ? na : 0.0f;
      w.y = (c0 + 1 == lab) ? na : 0.0f;
      w.z = (c0 + 2 == lab) ? na : 0.0f;
      w.w = (c0 + 3 == lab) ? na : 0.0f;
      ((float4*)(o2 + ((size_t)b * N_ + n) * C_))[j] = w;
    }
  }
}

// ---------------------------------------------------------------------------
extern "C" void kernel_launch(void* const* d_in, const int* in_sizes, int n_in,
                              void* d_out, int out_size, void* d_ws, size_t ws_size,
                              hipStream_t stream) {
  const float* pd_scores = (const float*)d_in[0];
  const float* pd_bboxes = (const float*)d_in[1];
  const float* anc       = (const float*)d_in[2];
  const int*   gt_labels = (const int*)d_in[3];
  const float* gt_bboxes = (const float*)d_in[4];
  const unsigned char* mask_raw = (const unsigned char*)d_in[5];

  char* ws = (char*)d_ws;
  size_t off = 0;
  double* CV  = (double*)(ws + off); off += (size_t)B_ * M_ * MAXC_ * 8;
  int*    CI  = (int*)(ws + off);    off += (size_t)B_ * M_ * MAXC_ * 4;
  unsigned int* MPB = (unsigned int*)(ws + off); off += (size_t)B_ * N_ * 4;
  unsigned int* CNT = (unsigned int*)(ws + off); off += (size_t)B_ * M_ * 4;
  unsigned int* PAL = (unsigned int*)(ws + off); off += (size_t)B_ * M_ * 4;
  unsigned int* POV = (unsigned int*)(ws + off); off += (size_t)B_ * M_ * 4;
  unsigned char* TG   = (unsigned char*)(ws + off); off += (size_t)B_ * N_;
  unsigned char* FG   = (unsigned char*)(ws + off); off += (size_t)B_ * N_;
  float* AMC = (float*)(ws + off); off += (size_t)B_ * N_ * 4;
  unsigned char* MASK = (unsigned char*)(ws + off); off += (size_t)B_ * M_;

  k_prep0<<<2, 256, 0, stream>>>(mask_raw, MASK, CNT, PAL, POV);
  dim3 gc((N_ + 255) / 256, B_, MZ_);
  k_cand<<<gc, 256, 0, stream>>>(pd_scores, pd_bboxes, anc, gt_labels,
                                 gt_bboxes, MASK, MPB, CNT, CV, CI);
  k_rowsel<<<(B_ * M_ + 3) / 4, 256, 0, stream>>>(CV, CI, CNT, anc, gt_bboxes,
                                                  MASK, MPB);
  dim3 gbn((N_ + 255) / 256, B_);
  k_colassign<<<gbn, 256, 0, stream>>>(pd_scores, pd_bboxes, anc, gt_labels,
                                       gt_bboxes, MASK, MPB,
                                       TG, FG, AMC, PAL, POV, (float*)d_out);
  dim3 gsc((N_ + 63) / 64, B_);
  k_sc<<<gsc, 256, 0, stream>>>(gt_labels, TG, FG, AMC, PAL, POV,
                                (float*)d_out);
}

// Round 10
// 161.599 us; speedup vs baseline: 1.0368x; 1.0368x over previous
//
#include <hip/hip_runtime.h>
#include <math.h>

#define B_ 16
#define N_ 8400
#define M_ 32
#define C_ 80
#define TOPK_ 13
#define MAXC_ 2048        // per-row candidate capacity (max possible ~1460)
#define MZ_ 4             // m-split factor for k_cand
#define MG_ (M_ / MZ_)    // 8 gts per k_cand block

// ---------------------------------------------------------------------------
__device__ __forceinline__ bool in_gt(double ax, double ay,
    double gx1, double gy1, double gx2, double gy2) {
  return (ax - gx1 > 1e-9) && (ay - gy1 > 1e-9) &&
         (gx2 - ax > 1e-9) && (gy2 - ay > 1e-9);
}

// CIoU clipped at 0 — identical formula/order as all passing rounds.
__device__ __forceinline__ double ciou_ov(
    double px1, double py1, double px2, double py2,
    double gx1, double gy1, double gx2, double gy2,
    double atp, double atg) {
  double iw = fmin(gx2, px2) - fmax(gx1, px1); iw = iw > 0.0 ? iw : 0.0;
  double ih = fmin(gy2, py2) - fmax(gy1, py1); ih = ih > 0.0 ? ih : 0.0;
  double inter = iw * ih;
  double w1 = gx2 - gx1, h1 = gy2 - gy1 + 1e-7;
  double w2 = px2 - px1, h2 = py2 - py1 + 1e-7;
  double uni = w1 * h1 + w2 * h2 - inter + 1e-7;
  double iou = inter / uni;
  double cw = fmax(gx2, px2) - fmin(gx1, px1);
  double ch = fmax(gy2, py2) - fmin(gy1, py1);
  double c2 = cw * cw + ch * ch + 1e-7;
  double dx = px1 + px2 - gx1 - gx2, dy = py1 + py2 - gy1 - gy2;
  double rho2 = (dx * dx + dy * dy) * 0.25;
  double dv = atp - atg;
  double v = (4.0 / (M_PI * M_PI)) * dv * dv;
  double a = v / (v - iou + (1.0 + 1e-7));
  double c = iou - (rho2 / c2 + v * a);
  return c > 0.0 ? c : 0.0;
}

// ---------------------------------------------------------------------------
// P0 (2 blocks): robust mask decode + zero CNT/PAL/POV.
__global__ __launch_bounds__(256) void k_prep0(
    const unsigned char* __restrict__ raw, unsigned char* __restrict__ mask,
    unsigned int* __restrict__ CNT,
    unsigned int* __restrict__ PAL, unsigned int* __restrict__ POV) {
  int gid = blockIdx.x * 256 + threadIdx.x;
  if (gid < B_ * M_) { CNT[gid] = 0u; PAL[gid] = 0u; POV[gid] = 0u; }
  if (blockIdx.x == 0) {
    __shared__ int s_bad;
    int t = threadIdx.x;
    if (t == 0) s_bad = 0;
    __syncthreads();
    if (t < B_) {
      int cnt = 0; bool seen0 = false; bool bad = false;
      for (int m = 0; m < M_; ++m) {
        unsigned char v = raw[t * M_ + m];
        if (v > 1) { bad = true; break; }
        if (v) { if (seen0) { bad = true; break; } ++cnt; }
        else seen0 = true;
      }
      if (cnt < 1) bad = true;
      if (bad) atomicOr(&s_bad, 1);
    }
    __syncthreads();
    bool ok = (s_bad == 0);
    const int* ri = (const int*)raw;
    for (int i = t; i < B_ * M_; i += 256)
      mask[i] = ok ? (raw[i] ? 1 : 0) : ((ri[i] != 0) ? 1 : 0);
  }
}

// ---------------------------------------------------------------------------
// K1: anchor-parallel candidate generation. grid (33, B, MZ_) = 2112 blocks.
// z==0 slice also zero-fills MPB (cand never reads it; rowsel runs after).
__global__ __launch_bounds__(256) void k_cand(
    const float* __restrict__ pd_scores, const float* __restrict__ pd_bboxes,
    const float* __restrict__ anc, const int* __restrict__ gt_labels,
    const float* __restrict__ gt_bboxes, const unsigned char* __restrict__ mask,
    unsigned int* __restrict__ MPB,
    unsigned int* __restrict__ CNT, double* __restrict__ CV,
    int* __restrict__ CI) {
  int b = blockIdx.y, t = threadIdx.x;
  int m0 = blockIdx.z * MG_;
  int n = blockIdx.x * 256 + t;

  if (blockIdx.z == 0 && n < N_) MPB[(size_t)b * N_ + n] = 0u;

  __shared__ double s_g[MG_][4];
  __shared__ double s_atg[MG_];
  __shared__ int s_cls[MG_];
  __shared__ unsigned char s_msk[MG_];
  __shared__ int s_any;
  if (t == 0) s_any = 0;
  __syncthreads();
  if (t < MG_) {
    int row = b * M_ + m0 + t;
    unsigned char mk = mask[row];
    s_msk[t] = mk;
    if (mk) atomicOr(&s_any, 1);
    double x1 = (double)gt_bboxes[row * 4 + 0], y1 = (double)gt_bboxes[row * 4 + 1];
    double x2 = (double)gt_bboxes[row * 4 + 2], y2 = (double)gt_bboxes[row * 4 + 3];
    s_g[t][0] = x1; s_g[t][1] = y1; s_g[t][2] = x2; s_g[t][3] = y2;
    s_atg[t] = atan((x2 - x1) / (y2 - y1 + 1e-7));
    s_cls[t] = gt_labels[row];
  }
  __syncthreads();
  if (!s_any) return;
  if (n >= N_) return;

  float2 a2 = ((const float2*)anc)[n];
  double ax = (double)a2.x, ay = (double)a2.y;
  bool have = false;
  double px1 = 0, py1 = 0, px2 = 0, py2 = 0, atpn = 0;
  const float* srow = pd_scores + ((size_t)b * N_ + n) * C_;

  for (int mm = 0; mm < MG_; ++mm) {
    if (!s_msk[mm]) continue;
    double gx1 = s_g[mm][0], gy1 = s_g[mm][1], gx2 = s_g[mm][2], gy2 = s_g[mm][3];
    if (!in_gt(ax, ay, gx1, gy1, gx2, gy2)) continue;
    if (!have) {
      float4 pb = ((const float4*)(pd_bboxes + (size_t)b * N_ * 4))[n];
      px1 = (double)pb.x; py1 = (double)pb.y;
      px2 = (double)pb.z; py2 = (double)pb.w;
      atpn = atan((px2 - px1) / ((py2 - py1) + 1e-7));
      have = true;
    }
    double ov = ciou_ov(px1, py1, px2, py2, gx1, gy1, gx2, gy2, atpn, s_atg[mm]);
    double o2 = ov * ov;
    double am = (double)srow[s_cls[mm]] * (o2 * o2 * o2);
    int row = b * M_ + m0 + mm;
    unsigned int idx = atomicAdd(&CNT[row], 1u);
    if (idx < MAXC_) {
      CV[(size_t)row * MAXC_ + idx] = am;
      CI[(size_t)row * MAXC_ + idx] = n;
    }
  }
}

// ---------------------------------------------------------------------------
// K2: one wave per row. Per-lane sorted top-13, then a 13-round
// argmax-of-heads pop merge (shfl reduce; no LDS, no list copies, no spill).
// Positives form a prefix; zero-fill computed per-lane from broadcast
// positive indices. All register indices static.
__global__ __launch_bounds__(64) void k_rowsel(
    const double* __restrict__ CV, const int* __restrict__ CI,
    const unsigned int* __restrict__ CNT,
    const float* __restrict__ anc, const float* __restrict__ gt_bboxes,
    const unsigned char* __restrict__ mask, unsigned int* __restrict__ MPB) {
  int row = blockIdx.x;
  if (!mask[row]) return;
  int lane = threadIdx.x;
  int b = row >> 5, m = row & 31;
  int cnt = (int)CNT[row]; if (cnt > MAXC_) cnt = MAXC_;
  const double* cv = CV + (size_t)row * MAXC_;
  const int*    ci = CI + (size_t)row * MAXC_;

  double tv[TOPK_]; int ti[TOPK_];
#pragma unroll
  for (int j = 0; j < TOPK_; ++j) { tv[j] = -1.0; ti[j] = 0x7fffffff; }

  for (int i = lane; i < cnt; i += 64) {
    double v = cv[i]; int idx = ci[i];
    if (v > tv[TOPK_ - 1] || (v == tv[TOPK_ - 1] && idx < ti[TOPK_ - 1])) {
      double cvv = v; int cii = idx;
#pragma unroll
      for (int j = 0; j < TOPK_; ++j) {
        bool sw = (cvv > tv[j]) || (cvv == tv[j] && cii < ti[j]);
        double xv = tv[j]; int xi = ti[j];
        if (sw) { tv[j] = cvv; ti[j] = cii; cvv = xv; cii = xi; }
      }
    }
  }

  // 13-round pop merge: wave argmax of heads, winner lane shifts.
  double myv = -1.0; int myi = 0x7fffffff;
#pragma unroll
  for (int k = 0; k < TOPK_; ++k) {
    double hv = tv[0]; int hi = ti[0];
#pragma unroll
    for (int d = 1; d < 64; d <<= 1) {
      double ov = __shfl_xor(hv, d, 64);
      int    oi = __shfl_xor(hi, d, 64);
      if (ov > hv || (ov == hv && oi < hi)) { hv = ov; hi = oi; }
    }
    if (lane == k) { myv = hv; myi = hi; }     // lane k records k-th winner
    if (tv[0] == hv && ti[0] == hi) {          // unique winner lane pops
#pragma unroll
      for (int j = 0; j < TOPK_ - 1; ++j) { tv[j] = tv[j + 1]; ti[j] = ti[j + 1]; }
      tv[TOPK_ - 1] = -1.0; ti[TOPK_ - 1] = 0x7fffffff;
    }
  }

  // positives are a prefix (sorted desc): p = #(myv > 0) among lanes 0..12
  unsigned long long posm = __ballot(lane < TOPK_ && myv > 0.0);
  int p = __popcll(posm);
  // broadcast all 13 selected indices (static q) for membership tests
  int pi[TOPK_];
#pragma unroll
  for (int q = 0; q < TOPK_; ++q) pi[q] = __shfl(myi, q, 64);

  int target = -1;
  if (lane < TOPK_) {
    if (lane < p) {
      target = myi;                            // positive: valid by construction
    } else {
      // (lane-p+1)-th smallest n not among positives
      int need = lane - p + 1, nn = 0;
      while (true) {
        bool member = false;
#pragma unroll
        for (int q = 0; q < TOPK_; ++q) member |= (q < p && pi[q] == nn);
        if (!member) { if (--need == 0) break; }
        ++nn;
      }
      double gx1 = gt_bboxes[row * 4 + 0], gy1 = gt_bboxes[row * 4 + 1];
      double gx2 = gt_bboxes[row * 4 + 2], gy2 = gt_bboxes[row * 4 + 3];
      float2 a2 = ((const float2*)anc)[nn];
      if (in_gt((double)a2.x, (double)a2.y, gx1, gy1, gx2, gy2))
        target = nn;                           // fill: needs valid check
    }
  }
  if (target >= 0) atomicOr(&MPB[(size_t)b * N_ + target], 1u << m);
}

// ---------------------------------------------------------------------------
// K3: per (b,n) resolve assignment; ALSO writes labels/bboxes/fg/tg_idx
// outputs (independent of PAL/POV). Wave-cooperative cnt>1 argmax.
__global__ __launch_bounds__(256) void k_colassign(
    const float* __restrict__ pd_scores, const float* __restrict__ pd_bboxes,
    const float* __restrict__ anc, const int* __restrict__ gt_labels,
    const float* __restrict__ gt_bboxes, const unsigned char* __restrict__ mask,
    const unsigned int* __restrict__ MPB,
    unsigned char* __restrict__ TG, unsigned char* __restrict__ FG,
    float* __restrict__ AMC,
    unsigned int* __restrict__ PAL, unsigned int* __restrict__ POV,
    float* __restrict__ out) {
  int b = blockIdx.y;
  int t = threadIdx.x;
  int n = blockIdx.x * 256 + t;
  int lane = t & 63;
  bool act = (n < N_);

  __shared__ double s_g[M_][4];
  __shared__ double s_atg[M_];
  __shared__ int s_cls[M_];
  __shared__ unsigned char s_msk[M_];
  if (t < M_) {
    int gi = b * M_ + t;
    double x1 = (double)gt_bboxes[gi * 4 + 0], y1 = (double)gt_bboxes[gi * 4 + 1];
    double x2 = (double)gt_bboxes[gi * 4 + 2], y2 = (double)gt_bboxes[gi * 4 + 3];
    s_g[t][0] = x1; s_g[t][1] = y1; s_g[t][2] = x2; s_g[t][3] = y2;
    s_atg[t] = atan((x2 - x1) / (y2 - y1 + 1e-7));
    s_cls[t] = gt_labels[gi];
    s_msk[t] = mask[gi];
  }
  __syncthreads();

  size_t i = (size_t)b * N_ + (act ? n : 0);
  unsigned int mpb = act ? MPB[i] : 0u;
  int cnt = __popc(mpb);

  double ax = 0, ay = 0, px1 = 0, py1 = 0, px2 = 0, py2 = 0;
  if (act && cnt >= 1) {
    float2 a2 = ((const float2*)anc)[n];
    float4 pb = ((const float4*)(pd_bboxes + (size_t)b * N_ * 4))[n];
    ax = (double)a2.x; ay = (double)a2.y;
    px1 = (double)pb.x; py1 = (double)pb.y; px2 = (double)pb.z; py2 = (double)pb.w;
  }

  int tg = 0; unsigned char fg = 0; double ov = 0.0;

  if (act && cnt == 1) {
    fg = 1;
    tg = __ffs(mpb) - 1;
    double atpn = atan((px2 - px1) / ((py2 - py1) + 1e-7));
    double g0 = s_g[tg][0], g1 = s_g[tg][1], g2 = s_g[tg][2], g3 = s_g[tg][3];
    bool val = s_msk[tg] && in_gt(ax, ay, g0, g1, g2, g3);
    ov = val ? ciou_ov(px1, py1, px2, py2, g0, g1, g2, g3, atpn, s_atg[tg]) : 0.0;
  }

  // wave-cooperative handling of rare cnt>1 anchors
  unsigned long long flagged = __ballot(act && cnt > 1);
  while (flagged) {
    int src = __ffsll(flagged) - 1;
    flagged &= flagged - 1;
    double qx  = __shfl(ax, src, 64),  qy  = __shfl(ay, src, 64);
    double q1  = __shfl(px1, src, 64), q2  = __shfl(py1, src, 64);
    double q3  = __shfl(px2, src, 64), q4  = __shfl(py2, src, 64);
    double atq = atan((q3 - q1) / ((q4 - q2) + 1e-7));
    int mm = lane & 31;
    double g0 = s_g[mm][0], g1 = s_g[mm][1], g2 = s_g[mm][2], g3 = s_g[mm][3];
    bool val = s_msk[mm] && in_gt(qx, qy, g0, g1, g2, g3);
    double o = val ? ciou_ov(q1, q2, q3, q4, g0, g1, g2, g3, atq, s_atg[mm]) : 0.0;
    int cm = mm;
#pragma unroll
    for (int d = 1; d < 32; d <<= 1) {
      double oo = __shfl_xor(o, d, 64);
      int    om = __shfl_xor(cm, d, 64);
      if (oo > o || (oo == o && om < cm)) { o = oo; cm = om; }
    }
    if (lane == src) { fg = 1; tg = cm; ov = o; }
  }

  if (!act) return;

  TG[i] = (unsigned char)tg;
  FG[i] = fg;
  if (fg) {
    double o2 = ov * ov;
    double am = (double)pd_scores[i * C_ + s_cls[tg]] * (o2 * o2 * o2);
    float ovf = (float)ov, amf = (float)am;
    AMC[i] = amf;
    atomicMax(&PAL[b * M_ + tg], __float_as_uint(amf));
    atomicMax(&POV[b * M_ + tg], __float_as_uint(ovf));
  }

  // aux outputs (independent of PAL/POV)
  float* o0 = out;                         // labels  (B,N)
  float* o1 = out + (size_t)B_ * N_;       // bboxes  (B,N,4)
  float* o3 = out + (size_t)B_ * N_ * 85;  // fg_mask (B,N)
  float* o4 = out + (size_t)B_ * N_ * 86;  // tg_idx  (B,N)
  o0[i] = (float)s_cls[tg];
  o3[i] = fg ? 1.0f : 0.0f;
  o4[i] = (float)tg;
  ((float4*)o1)[i] = make_float4((float)s_g[tg][0], (float)s_g[tg][1],
                                 (float)s_g[tg][2], (float)s_g[tg][3]);
}

// ---------------------------------------------------------------------------
// K4: score stream writer only (43MB), one-hot x norm_align.
__global__ __launch_bounds__(256) void k_sc(
    const int* __restrict__ gt_labels,
    const unsigned char* __restrict__ TG, const unsigned char* __restrict__ FG,
    const float* __restrict__ AMC,
    const unsigned int* __restrict__ PAL, const unsigned int* __restrict__ POV,
    float* __restrict__ out) {
  int b = blockIdx.y;
  int n0 = blockIdx.x * 64;
  int t = threadIdx.x;

  __shared__ int s_cls[M_];
  __shared__ float s_pal[M_], s_pov[M_];
  __shared__ float s_na[64];
  __shared__ int   s_lab[64];
  if (t < M_) {
    int gi = b * M_ + t;
    s_cls[t] = gt_labels[gi];
    s_pal[t] = __uint_as_float(PAL[gi]);
    s_pov[t] = __uint_as_float(POV[gi]);
  }
  __syncthreads();

  if (t < 64) {
    int n = n0 + t;
    if (n < N_) {
      size_t i = (size_t)b * N_ + n;
      int tg = TG[i];
      float na = 0.0f;
      if (FG[i]) {
        double am = (double)AMC[i];
        na = (float)(am * (double)s_pov[tg] / ((double)s_pal[tg] + 1e-9));
      }
      s_na[t] = na; s_lab[t] = s_cls[tg];
    }
  }
  __syncthreads();

  float* o2 = out + (size_t)B_ * N_ * 5;   // scores (B,N,C)
#pragma unroll
  for (int k = 0; k < 5; ++k) {
    int id = t + k * 256;
    int a = id / 20, j = id % 20;
    int n = n0 + a;
    if (n < N_) {
      int lab = s_lab[a];
      float na = s_na[a];
      int c0 = 4 * j;
      float4 w;
      w.x = (c0 + 0 == lab) ? na : 0.0f;
      w.y = (c0 + 1 == lab) ? na : 0.0f;
      w.z = (c0 + 2 == lab) ? na : 0.0f;
      w.w = (c0 + 3 == lab) ? na : 0.0f;
      ((float4*)(o2 + ((size_t)b * N_ + n) * C_))[j] = w;
    }
  }
}

// ---------------------------------------------------------------------------
extern "C" void kernel_launch(void* const* d_in, const int* in_sizes, int n_in,
                              void* d_out, int out_size, void* d_ws, size_t ws_size,
                              hipStream_t stream) {
  const float* pd_scores = (const float*)d_in[0];
  const float* pd_bboxes = (const float*)d_in[1];
  const float* anc       = (const float*)d_in[2];
  const int*   gt_labels = (const int*)d_in[3];
  const float* gt_bboxes = (const float*)d_in[4];
  const unsigned char* mask_raw = (const unsigned char*)d_in[5];

  char* ws = (char*)d_ws;
  size_t off = 0;
  double* CV  = (double*)(ws + off); off += (size_t)B_ * M_ * MAXC_ * 8;
  int*    CI  = (int*)(ws + off);    off += (size_t)B_ * M_ * MAXC_ * 4;
  unsigned int* MPB = (unsigned int*)(ws + off); off += (size_t)B_ * N_ * 4;
  unsigned int* CNT = (unsigned int*)(ws + off); off += (size_t)B_ * M_ * 4;
  unsigned int* PAL = (unsigned int*)(ws + off); off += (size_t)B_ * M_ * 4;
  unsigned int* POV = (unsigned int*)(ws + off); off += (size_t)B_ * M_ * 4;
  unsigned char* TG   = (unsigned char*)(ws + off); off += (size_t)B_ * N_;
  unsigned char* FG   = (unsigned char*)(ws + off); off += (size_t)B_ * N_;
  float* AMC = (float*)(ws + off); off += (size_t)B_ * N_ * 4;
  unsigned char* MASK = (unsigned char*)(ws + off); off += (size_t)B_ * M_;

  k_prep0<<<2, 256, 0, stream>>>(mask_raw, MASK, CNT, PAL, POV);
  dim3 gc((N_ + 255) / 256, B_, MZ_);
  k_cand<<<gc, 256, 0, stream>>>(pd_scores, pd_bboxes, anc, gt_labels,
                                 gt_bboxes, MASK, MPB, CNT, CV, CI);
  k_rowsel<<<B_ * M_, 64, 0, stream>>>(CV, CI, CNT, anc, gt_bboxes,
                                       MASK, MPB);
  dim3 gbn((N_ + 255) / 256, B_);
  k_colassign<<<gbn, 256, 0, stream>>>(pd_scores, pd_bboxes, anc, gt_labels,
                                       gt_bboxes, MASK, MPB,
                                       TG, FG, AMC, PAL, POV, (float*)d_out);
  dim3 gsc((N_ + 63) / 64, B_);
  k_sc<<<gsc, 256, 0, stream>>>(gt_labels, TG, FG, AMC, PAL, POV,
                                (float*)d_out);
}